// Round 7
// baseline (250.677 us; speedup 1.0000x reference)
//
#include <hip/hip_runtime.h>
#include <hip/hip_bf16.h>
#include <stdint.h>

typedef unsigned int u32;
typedef unsigned short u16;
typedef __attribute__((ext_vector_type(8))) short short8;   // 8 bf16 = 4 VGPRs (MFMA A/B frag)
typedef __attribute__((ext_vector_type(4))) float f32x4;    // MFMA C/D frag

#define SCAN_TILE 2048   // elements per block in hierarchical scan (256 thr x 8)

__device__ __forceinline__ float bf2f(u16 u) {
    union { u32 u; float f; } v; v.u = ((u32)u) << 16; return v.f;
}
__device__ __forceinline__ u16 f2bf(float f) {
    u32 u = __float_as_uint(f);
    u32 r = (u + 0x7FFFu + ((u >> 16) & 1u)) >> 16;  // RNE
    return (u16)r;
}
__device__ __forceinline__ u32 packbf(float lo, float hi) {
    return ((u32)f2bf(hi) << 16) | (u32)f2bf(lo);
}

// Block 0: flags[0]=1 if float tensors are f32 (else bf16), flags[1]=1 if
// edge_index int64 (else int32). ALL blocks: zero deg[0..M).
__global__ __launch_bounds__(256) void detect_zero_k(const u32* __restrict__ xw,
                                                     const u32* __restrict__ ew,
                                                     int* __restrict__ flags,
                                                     int* __restrict__ deg, int M) {
    const int t = threadIdx.x;
    const int i4 = (blockIdx.x * 256 + t) * 4;
    if (i4 + 4 <= M) *(int4*)(deg + i4) = make_int4(0, 0, 0, 0);
    else { for (int j = 0; j < 4; j++) if (i4 + j < M) deg[i4 + j] = 0; }

    if (blockIdx.x == 0) {
        __shared__ int cnt;
        __shared__ u32 orr;
        if (t == 0) { cnt = 0; orr = 0u; }
        __syncthreads();
        int hits = 0;
        for (int i = t; i < 1024; i += 256) {
            u32 f = (xw[i] >> 7) & 0xFFu;
            if (f >= 100u && f <= 140u) hits++;
        }
        atomicAdd(&cnt, hits);
        atomicOr(&orr, ew[2 * t + 1]);
        __syncthreads();
        if (t == 0) {
            flags[0] = (cnt < 512) ? 1 : 0;
            flags[1] = (orr == 0u) ? 1 : 0;
        }
    }
}

// Pre-pack W into B-frag order: chunk p = kb*N+n holds 8 bf16 of col n,
// rows k = kb*8..+7.
template<int N>
__device__ __forceinline__ void wpack_one(const void* W, uint4* wpk, int p, int f32w) {
    const int n = p & (N - 1);
    const int kb = p >> ((N == 128) ? 7 : 6);
    u32 pk[4];
    if (f32w) {
        const float* wp = (const float*)W + (size_t)(kb * 8) * N + n;
        #pragma unroll
        for (int jj = 0; jj < 4; jj++)
            pk[jj] = packbf(wp[(2 * jj) * N], wp[(2 * jj + 1) * N]);
    } else {
        const u16* wp = (const u16*)W + (size_t)(kb * 8) * N + n;
        #pragma unroll
        for (int jj = 0; jj < 4; jj++)
            pk[jj] = ((u32)wp[(2 * jj + 1) * N] << 16) | (u32)wp[(2 * jj) * N];
    }
    uint4 v; v.x = pk[0]; v.y = pk[1]; v.z = pk[2]; v.w = pk[3];
    wpk[p] = v;
}

// blocks 0..7: W1 (128x128); blocks 8..11: W2 (128x64)
__global__ __launch_bounds__(256) void wpack_all_k(const void* __restrict__ W1,
                                                   const void* __restrict__ W2,
                                                   uint4* __restrict__ wpk1,
                                                   uint4* __restrict__ wpk2,
                                                   const int* __restrict__ flags) {
    const int b = blockIdx.x, t = threadIdx.x;
    const int f32w = flags[0];
    if (b < 8) wpack_one<128>(W1, wpk1, b * 256 + t, f32w);
    else       wpack_one<64> (W2, wpk2, (b - 8) * 256 + t, f32w);
}

__global__ __launch_bounds__(256) void count_deg_k(const void* __restrict__ ei, int E,
                                                   const int* __restrict__ flags,
                                                   int* __restrict__ deg) {
    int i = blockIdx.x * 256 + threadIdx.x;
    if (i >= E) return;
    int d = flags[1] ? (int)((const long long*)ei)[E + i] : ((const int*)ei)[E + i];
    atomicAdd(&deg[d], 1);
}

// ---- hierarchical exclusive scan of deg[0..M) -> off/cursor, plus dinv ----
__global__ __launch_bounds__(256) void scan_partial_k(const int* __restrict__ deg, int M,
                                                      int* __restrict__ bsum) {
    const int t = threadIdx.x;
    const int base = blockIdx.x * SCAN_TILE + t * 8;
    int s = 0;
    if (base + 8 <= M) {
        int4 a = *(const int4*)(deg + base);
        int4 b = *(const int4*)(deg + base + 4);
        s = a.x + a.y + a.z + a.w + b.x + b.y + b.z + b.w;
    } else {
        for (int j = 0; j < 8; j++) if (base + j < M) s += deg[base + j];
    }
    __shared__ int red[256];
    red[t] = s;
    __syncthreads();
    for (int d = 128; d > 0; d >>= 1) {
        if (t < d) red[t] += red[t + d];
        __syncthreads();
    }
    if (t == 0) bsum[blockIdx.x] = red[0];
}

__global__ __launch_bounds__(256) void scan_bsum_k(int* __restrict__ bsum, int nb,
                                                   int* __restrict__ off, int M) {
    __shared__ int buf[2][256];
    const int t = threadIdx.x;
    int v = (t < nb) ? bsum[t] : 0;
    const int own = v;
    buf[0][t] = v;
    __syncthreads();
    int cur = 0;
    for (int d = 1; d < 256; d <<= 1) {
        int x = buf[cur][t];
        if (t >= d) x += buf[cur][t - d];
        buf[cur ^ 1][t] = x;
        __syncthreads();
        cur ^= 1;
    }
    if (t < nb) bsum[t] = buf[cur][t] - own;          // exclusive
    if (t == 255) off[M] = buf[cur][255];             // grand total
}

__global__ __launch_bounds__(256) void scan_final_k(const int* __restrict__ deg,
                                                    const int* __restrict__ bsum, int M,
                                                    int* __restrict__ off,
                                                    int* __restrict__ cursor,
                                                    float* __restrict__ dinv) {
    const int t = threadIdx.x;
    const int base = blockIdx.x * SCAN_TILE + t * 8;
    int v[8];
    int s = 0;
    const bool full = (base + 8 <= M);
    if (full) {
        int4 a = *(const int4*)(deg + base);
        int4 b = *(const int4*)(deg + base + 4);
        v[0] = a.x; v[1] = a.y; v[2] = a.z; v[3] = a.w;
        v[4] = b.x; v[5] = b.y; v[6] = b.z; v[7] = b.w;
        s = v[0] + v[1] + v[2] + v[3] + v[4] + v[5] + v[6] + v[7];
    } else {
        #pragma unroll
        for (int j = 0; j < 8; j++) { v[j] = (base + j < M) ? deg[base + j] : 0; s += v[j]; }
    }
    __shared__ int buf[2][256];
    buf[0][t] = s;
    __syncthreads();
    int cur = 0;
    for (int d = 1; d < 256; d <<= 1) {
        int x = buf[cur][t];
        if (t >= d) x += buf[cur][t - d];
        buf[cur ^ 1][t] = x;
        __syncthreads();
        cur ^= 1;
    }
    int pre = bsum[blockIdx.x] + buf[cur][t] - s;
    int o[8]; float dv[8];
    #pragma unroll
    for (int j = 0; j < 8; j++) {
        o[j] = pre;
        dv[j] = rsqrtf((float)(v[j] + 1));            // +1 self-loop
        pre += v[j];
    }
    if (full) {
        *(int4*)(off + base)     = make_int4(o[0], o[1], o[2], o[3]);
        *(int4*)(off + base + 4) = make_int4(o[4], o[5], o[6], o[7]);
        *(int4*)(cursor + base)     = make_int4(o[0], o[1], o[2], o[3]);
        *(int4*)(cursor + base + 4) = make_int4(o[4], o[5], o[6], o[7]);
        *(float4*)(dinv + base)     = make_float4(dv[0], dv[1], dv[2], dv[3]);
        *(float4*)(dinv + base + 4) = make_float4(dv[4], dv[5], dv[6], dv[7]);
    } else {
        for (int j = 0; j < 8; j++) if (base + j < M) {
            off[base + j] = o[j]; cursor[base + j] = o[j]; dinv[base + j] = dv[j];
        }
    }
}

__global__ __launch_bounds__(256) void fill_k(const void* __restrict__ ei, int E,
                                              const int* __restrict__ flags,
                                              int* __restrict__ cursor, int* __restrict__ eidx) {
    int i = blockIdx.x * 256 + threadIdx.x;
    if (i >= E) return;
    int s, d;
    if (flags[1]) { const long long* p = (const long long*)ei; s = (int)p[i]; d = (int)p[E + i]; }
    else          { const int* p = (const int*)ei;             s = p[i];      d = p[E + i]; }
    int pos = atomicAdd(&cursor[d], 1);
    eidx[pos] = s;
}

// ===== MFMA GEMM: HS[m,:] = bf16( (X[m,:] @ W) * dinv[m] ), K=128 =====
template<int N>
__global__ __launch_bounds__(256) void gemm_mfma_k(
    const void* __restrict__ X, const uint4* __restrict__ wpk,
    const float* __restrict__ dinv, u16* __restrict__ HS,
    const int* __restrict__ flags, int x_is_ext, int M)
{
    constexpr int NT = N / 16;                  // n-tiles
    constexpr int NC8 = N / 8;                  // 16B chunks per output row
    __shared__ u32 xlds[128 * 64];              // 128 rows x 256B bf16 (32 KB)
    const int t = threadIdx.x;
    const int wave = t >> 6, lane = t & 63;
    const int q = lane >> 4, m = lane & 15;
    const bool xf32 = (x_is_ext != 0) && (flags[0] != 0);
    const int row0 = blockIdx.x * 128;

    // ---- stage X tile -> LDS (coalesced; 2048 chunks of 16B bf16) ----
    for (int c = t; c < 2048; c += 256) {
        const int row = c >> 4, c8 = c & 15;
        const int grow = row0 + row;
        uint4 pk = make_uint4(0u, 0u, 0u, 0u);
        if (grow < M) {
            if (xf32) {
                const float* xp = (const float*)X + (size_t)grow * 128 + c8 * 8;
                float4 u = *(const float4*)xp;
                float4 v = *(const float4*)(xp + 4);
                pk.x = packbf(u.x, u.y); pk.y = packbf(u.z, u.w);
                pk.z = packbf(v.x, v.y); pk.w = packbf(v.z, v.w);
            } else {
                pk = *(const uint4*)((const u16*)X + (size_t)grow * 128 + c8 * 8);
            }
        }
        *(uint4*)&xlds[row * 64 + c8 * 4] = pk;
    }
    __syncthreads();

    // ---- A-fragments from LDS (wave's own 32 rows) ----
    union { uint4 u; short8 v; } a[2][4];
    #pragma unroll
    for (int rt = 0; rt < 2; rt++)
        #pragma unroll
        for (int s = 0; s < 4; s++)
            a[rt][s].u = *(const uint4*)&xlds[(wave * 32 + rt * 16 + m) * 64 + (s * 4 + q) * 4];

    // ---- MFMA loop; B-frags direct from global wpk (L2-resident) ----
    f32x4 acc[2][NT];
    #pragma unroll
    for (int rt = 0; rt < 2; rt++)
        #pragma unroll
        for (int tt = 0; tt < NT; tt++)
            acc[rt][tt] = (f32x4){0.f, 0.f, 0.f, 0.f};

    #pragma unroll
    for (int s = 0; s < 4; s++) {
        union { uint4 u; short8 v; } b[NT];
        #pragma unroll
        for (int tt = 0; tt < NT; tt++)
            b[tt].u = wpk[(s * 4 + q) * N + tt * 16 + m];
        #pragma unroll
        for (int tt = 0; tt < NT; tt++)
            #pragma unroll
            for (int rt = 0; rt < 2; rt++)
                acc[rt][tt] = __builtin_amdgcn_mfma_f32_16x16x32_bf16(
                    a[rt][s].v, b[tt].v, acc[rt][tt], 0, 0, 0);
    }

    // ---- epilogue: dinv scale, repack via wave-private LDS, 16B stores ----
    float dv[2][4];
    #pragma unroll
    for (int rt = 0; rt < 2; rt++)
        #pragma unroll
        for (int r = 0; r < 4; r++) {
            const int grow = row0 + wave * 32 + rt * 16 + q * 4 + r;
            dv[rt][r] = (grow < M) ? dinv[grow] : 0.f;
        }

    u16* orow = (u16*)&xlds[wave * 32 * 64];    // wave-private 8KB region
    #pragma unroll
    for (int rt = 0; rt < 2; rt++)
        #pragma unroll
        for (int tt = 0; tt < NT; tt++)
            #pragma unroll
            for (int r = 0; r < 4; r++)
                orow[(rt * 16 + q * 4 + r) * N + tt * 16 + m] =
                    f2bf(acc[rt][tt][r] * dv[rt][r]);

    constexpr int ITER = 16 * NC8 / 64;         // 4 (N=128) / 2 (N=64)
    #pragma unroll
    for (int rt = 0; rt < 2; rt++) {
        #pragma unroll
        for (int j = 0; j < ITER; j++) {
            const int cc = lane + j * 64;
            const int lrow = cc / NC8, c8 = cc % NC8;
            const int grow = row0 + wave * 32 + rt * 16 + lrow;
            uint4 v = *(const uint4*)&((const u32*)orow)[(rt * 16 + lrow) * (N / 2) + c8 * 4];
            if (grow < M)
                *(uint4*)(HS + (size_t)grow * N + c8 * 8) = v;
        }
    }
}

// ===== FUSED: z = relu(dinv*(agg hs1)+b1) into LDS, then hs2 = (z@W2)*dinv =====
// Block = 256 thr / 4 waves, 128 nodes. Phase 1: 16 lanes/node, 8 batches,
// z-tile (128x128 bf16) in LDS. Phase 2: gemm_mfma<64> body reading LDS.
__global__ __launch_bounds__(256) void agg_gemm_k(
    const u16* __restrict__ hs, const int* __restrict__ eidx,
    const int* __restrict__ off, const float* __restrict__ dinv,
    const void* __restrict__ bias, const uint4* __restrict__ wpk2,
    u16* __restrict__ HS2, const int* __restrict__ flags, int M)
{
    __shared__ u32 zlds[128 * 64];              // 128 rows x 128 bf16 (32 KB)
    const int t = threadIdx.x;
    const int wave = t >> 6, lane = t & 63;
    const int q = lane >> 4, m = lane & 15;
    const int row0 = blockIdx.x * 128;
    const int f32io = flags[0];
    const int l16 = t & 15, c8 = l16 * 8;
    const u16* __restrict__ hrow = hs + c8;

    // bias for this thread's 8 cols (layer-1 bias)
    float b[8];
    if (f32io) {
        float4 u = *(const float4*)((const float*)bias + c8);
        float4 v = *(const float4*)((const float*)bias + c8 + 4);
        b[0] = u.x; b[1] = u.y; b[2] = u.z; b[3] = u.w;
        b[4] = v.x; b[5] = v.y; b[6] = v.z; b[7] = v.w;
    } else {
        uint4 u = *(const uint4*)((const u16*)bias + c8);
        const u16* s = (const u16*)&u;
        #pragma unroll
        for (int j = 0; j < 8; j++) b[j] = bf2f(s[j]);
    }

    // ---- phase 1: aggregate 128 nodes (16 per batch) ----
    for (int it = 0; it < 8; it++) {
        const int lr = it * 16 + (t >> 4);
        const int node = row0 + lr;
        uint4 zpk = make_uint4(0u, 0u, 0u, 0u);
        if (node < M) {
            float a[8];
            {
                uint4 sp = *(const uint4*)(hrow + (size_t)node * 128);  // self-loop
                const u16* s = (const u16*)&sp;
                #pragma unroll
                for (int j = 0; j < 8; j++) a[j] = bf2f(s[j]);
            }
            const int beg = off[node], end = off[node + 1];
            int p = beg;
            for (; p + 4 <= end; p += 4) {
                const int s0 = eidx[p + 0], s1 = eidx[p + 1];
                const int s2 = eidx[p + 2], s3 = eidx[p + 3];
                uint4 v0 = *(const uint4*)(hrow + (size_t)s0 * 128);
                uint4 v1 = *(const uint4*)(hrow + (size_t)s1 * 128);
                uint4 v2 = *(const uint4*)(hrow + (size_t)s2 * 128);
                uint4 v3 = *(const uint4*)(hrow + (size_t)s3 * 128);
                const u16* q0 = (const u16*)&v0; const u16* q1 = (const u16*)&v1;
                const u16* q2 = (const u16*)&v2; const u16* q3 = (const u16*)&v3;
                #pragma unroll
                for (int j = 0; j < 8; j++)
                    a[j] += (bf2f(q0[j]) + bf2f(q1[j])) + (bf2f(q2[j]) + bf2f(q3[j]));
            }
            for (; p < end; p++) {
                const int s = eidx[p];
                uint4 v = *(const uint4*)(hrow + (size_t)s * 128);
                const u16* qq = (const u16*)&v;
                #pragma unroll
                for (int j = 0; j < 8; j++) a[j] += bf2f(qq[j]);
            }
            const float dv = dinv[node];
            float z[8];
            #pragma unroll
            for (int j = 0; j < 8; j++) z[j] = fmaxf(fmaf(dv, a[j], b[j]), 0.f);
            zpk.x = packbf(z[0], z[1]); zpk.y = packbf(z[2], z[3]);
            zpk.z = packbf(z[4], z[5]); zpk.w = packbf(z[6], z[7]);
        }
        *(uint4*)&zlds[lr * 64 + l16 * 4] = zpk;
    }
    __syncthreads();

    // ---- phase 2: hs2 = (z @ W2) * dinv, N=64, straight out of LDS ----
    union { uint4 u; short8 v; } a[2][4];
    #pragma unroll
    for (int rt = 0; rt < 2; rt++)
        #pragma unroll
        for (int s = 0; s < 4; s++)
            a[rt][s].u = *(const uint4*)&zlds[(wave * 32 + rt * 16 + m) * 64 + (s * 4 + q) * 4];

    f32x4 acc[2][4];
    #pragma unroll
    for (int rt = 0; rt < 2; rt++)
        #pragma unroll
        for (int tt = 0; tt < 4; tt++)
            acc[rt][tt] = (f32x4){0.f, 0.f, 0.f, 0.f};

    #pragma unroll
    for (int s = 0; s < 4; s++) {
        union { uint4 u; short8 v; } bb[4];
        #pragma unroll
        for (int tt = 0; tt < 4; tt++)
            bb[tt].u = wpk2[(s * 4 + q) * 64 + tt * 16 + m];
        #pragma unroll
        for (int tt = 0; tt < 4; tt++)
            #pragma unroll
            for (int rt = 0; rt < 2; rt++)
                acc[rt][tt] = __builtin_amdgcn_mfma_f32_16x16x32_bf16(
                    a[rt][s].v, bb[tt].v, acc[rt][tt], 0, 0, 0);
    }

    float dv2[2][4];
    #pragma unroll
    for (int rt = 0; rt < 2; rt++)
        #pragma unroll
        for (int r = 0; r < 4; r++) {
            const int grow = row0 + wave * 32 + rt * 16 + q * 4 + r;
            dv2[rt][r] = (grow < M) ? dinv[grow] : 0.f;
        }

    u16* orow = (u16*)&zlds[wave * 32 * 64];    // wave-private 8KB region
    #pragma unroll
    for (int rt = 0; rt < 2; rt++)
        #pragma unroll
        for (int tt = 0; tt < 4; tt++)
            #pragma unroll
            for (int r = 0; r < 4; r++)
                orow[(rt * 16 + q * 4 + r) * 64 + tt * 16 + m] =
                    f2bf(acc[rt][tt][r] * dv2[rt][r]);

    #pragma unroll
    for (int rt = 0; rt < 2; rt++) {
        #pragma unroll
        for (int j = 0; j < 2; j++) {           // 16 rows x 8 chunks / 64 lanes
            const int cc = lane + j * 64;
            const int lrow = cc >> 3, c = cc & 7;
            const int grow = row0 + wave * 32 + rt * 16 + lrow;
            uint4 v = *(const uint4*)&((const u32*)orow)[(rt * 16 + lrow) * 32 + c * 4];
            if (grow < M)
                *(uint4*)(HS2 + (size_t)grow * 64 + c * 8) = v;
        }
    }
}

// out[i,:] = dinv[i] * (sum hs[j,:] + hs[i,:]) + bias   (final layer, no relu)
template<int N, bool RELU>
__global__ __launch_bounds__(256) void aggregate_k(
    const u16* __restrict__ hs, const int* __restrict__ eidx,
    const int* __restrict__ off, const float* __restrict__ dinv,
    const void* __restrict__ bias, void* __restrict__ out,
    const int* __restrict__ flags, int out_is_ext, int M)
{
    constexpr int TPN = N / 8;               // threads per node, 8 cols each
    constexpr int NPB = 256 / TPN;
    const int node = blockIdx.x * NPB + threadIdx.x / TPN;
    const int lane = threadIdx.x % TPN;
    if (node >= M) return;
    const int f32io = flags[0];
    const int beg = off[node], end = off[node + 1];
    const int c8 = lane * 8;
    const u16* __restrict__ hrow = hs + c8;

    float a[8];
    {
        uint4 sp = *(const uint4*)(hrow + (size_t)node * N);   // self-loop term
        const u16* s = (const u16*)&sp;
        #pragma unroll
        for (int j = 0; j < 8; j++) a[j] = bf2f(s[j]);
    }

    int p = beg;
    for (; p + 4 <= end; p += 4) {
        const int s0 = eidx[p + 0], s1 = eidx[p + 1];
        const int s2 = eidx[p + 2], s3 = eidx[p + 3];
        uint4 v0 = *(const uint4*)(hrow + (size_t)s0 * N);
        uint4 v1 = *(const uint4*)(hrow + (size_t)s1 * N);
        uint4 v2 = *(const uint4*)(hrow + (size_t)s2 * N);
        uint4 v3 = *(const uint4*)(hrow + (size_t)s3 * N);
        const u16* q0 = (const u16*)&v0; const u16* q1 = (const u16*)&v1;
        const u16* q2 = (const u16*)&v2; const u16* q3 = (const u16*)&v3;
        #pragma unroll
        for (int j = 0; j < 8; j++)
            a[j] += (bf2f(q0[j]) + bf2f(q1[j])) + (bf2f(q2[j]) + bf2f(q3[j]));
    }
    for (; p < end; p++) {
        const int s = eidx[p];
        uint4 v = *(const uint4*)(hrow + (size_t)s * N);
        const u16* q = (const u16*)&v;
        #pragma unroll
        for (int j = 0; j < 8; j++) a[j] += bf2f(q[j]);
    }

    const float dv = dinv[node];
    float b[8];
    if (f32io) {
        float4 u = *(const float4*)((const float*)bias + c8);
        float4 v = *(const float4*)((const float*)bias + c8 + 4);
        b[0] = u.x; b[1] = u.y; b[2] = u.z; b[3] = u.w;
        b[4] = v.x; b[5] = v.y; b[6] = v.z; b[7] = v.w;
    } else {
        uint4 u = *(const uint4*)((const u16*)bias + c8);
        const u16* s = (const u16*)&u;
        #pragma unroll
        for (int j = 0; j < 8; j++) b[j] = bf2f(s[j]);
    }
    float o[8];
    #pragma unroll
    for (int j = 0; j < 8; j++) {
        o[j] = fmaf(dv, a[j], b[j]);
        if (RELU) o[j] = fmaxf(o[j], 0.f);
    }
    if (out_is_ext && f32io) {
        float* op = (float*)out + (size_t)node * N + c8;
        *(float4*)op       = make_float4(o[0], o[1], o[2], o[3]);
        *(float4*)(op + 4) = make_float4(o[4], o[5], o[6], o[7]);
    } else {
        uint4 pk;
        pk.x = packbf(o[0], o[1]); pk.y = packbf(o[2], o[3]);
        pk.z = packbf(o[4], o[5]); pk.w = packbf(o[6], o[7]);
        *(uint4*)((u16*)out + (size_t)node * N + c8) = pk;
    }
}

extern "C" void kernel_launch(void* const* d_in, const int* in_sizes, int n_in,
                              void* d_out, int out_size, void* d_ws, size_t ws_size,
                              hipStream_t stream) {
    const void* x  = d_in[0];
    const void* ei = d_in[1];
    const void* W1 = d_in[2];
    const void* b1 = d_in[3];
    const void* W2 = d_in[4];
    const void* b2 = d_in[5];

    const int M = in_sizes[0] / 128;   // 100000 nodes
    const int E = in_sizes[1] / 2;     // 600000 edges
    const int NB = (M + SCAN_TILE - 1) / SCAN_TILE;

    char* ws = (char*)d_ws;
    size_t offb = 0;
    auto alloc = [&](size_t bytes) -> void* {
        void* p = ws + offb; offb += (bytes + 255) & ~(size_t)255; return p;
    };
    int*   flags  = (int*)  alloc(256);
    int*   bsum   = (int*)  alloc(1024);
    uint4* wpk1   = (uint4*)alloc(16 * 128 * 16);         // 32 KB packed W1
    uint4* wpk2   = (uint4*)alloc(16 * 64 * 16);          // 16 KB packed W2
    int*   deg    = (int*)  alloc((size_t)M * 4);
    int*   off    = (int*)  alloc((size_t)(M + 1) * 4);
    int*   cursor = (int*)  alloc((size_t)M * 4);
    float* dinv   = (float*)alloc((size_t)M * 4);
    int*   eidx   = (int*)  alloc((size_t)E * 4);
    u16*   hs1    = (u16*)  alloc((size_t)M * 128 * 2);   // 25.6 MB
    u16*   hs2    = (u16*)  alloc((size_t)M * 64 * 2);    // 12.8 MB
    (void)ws_size; (void)n_in; (void)out_size;

    detect_zero_k<<<(M + 1023) / 1024, 256, 0, stream>>>((const u32*)x, (const u32*)ei,
                                                         flags, deg, M);
    wpack_all_k<<<12, 256, 0, stream>>>(W1, W2, wpk1, wpk2, flags);
    count_deg_k<<<(E + 255) / 256, 256, 0, stream>>>(ei, E, flags, deg);
    scan_partial_k<<<NB, 256, 0, stream>>>(deg, M, bsum);
    scan_bsum_k<<<1, 256, 0, stream>>>(bsum, NB, off, M);
    scan_final_k<<<NB, 256, 0, stream>>>(deg, bsum, M, off, cursor, dinv);
    fill_k<<<(E + 255) / 256, 256, 0, stream>>>(ei, E, flags, cursor, eidx);

    // layer 1 GEMM: hs1 = (x @ W1) * dinv
    gemm_mfma_k<128><<<(M + 127) / 128, 256, 0, stream>>>(x, wpk1, dinv, hs1, flags, 1, M);
    // fused: z = relu(dinv*agg(hs1)+b1); hs2 = (z @ W2) * dinv
    agg_gemm_k<<<(M + 127) / 128, 256, 0, stream>>>(hs1, eidx, off, dinv, b1, wpk2, hs2,
                                                    flags, M);
    // final aggregate: out = dinv*agg(hs2) + b2
    aggregate_k<64, false><<<(M + 31) / 32, 256, 0, stream>>>(hs2, eidx, off, dinv, b2, d_out,
                                                              flags, 1, M);
}